// Round 6
// baseline (248.139 us; speedup 1.0000x reference)
//
#include <hip/hip_runtime.h>

// B=8, L=1024, H=1024, NH=16, HD=64. fp32 I/O, bf16 MFMA internals.
// Pipeline: cvt3     : x,w_qkv,w_out fp32 -> bf16                  (~13 us)
//           gemm16<0>: qk = x@w_qkv^T cols<2048; V scatters to Vt  (51.5 GF)
//           attn     : no-max softmax flash attn, S^T trick        (34.4 GF)
//           gemm16<1>: out = O@w_out^T + b_out (fp32 out)          (17.2 GF)
// R6: attn grid is XCD-aware — grid(128 bh, 8 qtile) so linear id % 8 = bh % 8:
// all 8 q-tiles sharing one head's K/V co-locate on one XCD L2 (K/V fetched
// once per XCD, not 8x from HBM). Single per-wave P buffer (LDS in-order per
// wave makes the double buffer redundant): 25.2 KB -> 6 blocks/CU.

typedef short s16x8 __attribute__((ext_vector_type(8)));
typedef float f32x4 __attribute__((ext_vector_type(4)));
typedef unsigned int u32x2 __attribute__((ext_vector_type(2)));
typedef unsigned int u32x4 __attribute__((ext_vector_type(4)));

__device__ __forceinline__ unsigned short f2bf(float f) {   // RNE
    union { float f; unsigned u; } c; c.f = f;
    return (unsigned short)((c.u + 0x7FFFu + ((c.u >> 16) & 1u)) >> 16);
}
// pack 2 floats -> 2 bf16 (round-half-up) in 3 VALU ops via v_perm
__device__ __forceinline__ unsigned pack2bf(float a, float b) {
    union { float f; unsigned u; } ca, cb; ca.f = a; cb.f = b;
    return __builtin_amdgcn_perm(cb.u + 0x8000u, ca.u + 0x8000u, 0x07060302u);
}

#define GLOAD_LDS(g, l) __builtin_amdgcn_global_load_lds( \
    (const __attribute__((address_space(1))) void*)(g),   \
    (__attribute__((address_space(3))) void*)(l), 16, 0, 0)

// ---------------------------------------------------------------------------
// fp32 -> bf16 convert for the three input tensors.
// ---------------------------------------------------------------------------
__global__ __launch_bounds__(256) void cvt3(
    const float* __restrict__ s0, unsigned short* __restrict__ d0, int n0,
    const float* __restrict__ s1, unsigned short* __restrict__ d1, int n1,
    const float* __restrict__ s2, unsigned short* __restrict__ d2, int n2)
{
    long i = ((long)blockIdx.x * 256 + threadIdx.x) * 8;
    const float* s; unsigned short* d; long off;
    if (i < n0)                  { s = s0; d = d0; off = i; }
    else if (i < (long)n0 + n1)  { s = s1; d = d1; off = i - n0; }
    else                         { s = s2; d = d2; off = i - n0 - n1; }
    f32x4 a = *(const f32x4*)(s + off);
    f32x4 b = *(const f32x4*)(s + off + 4);
    u32x4 r;
    r[0] = pack2bf(a[0], a[1]); r[1] = pack2bf(a[2], a[3]);
    r[2] = pack2bf(b[0], b[1]); r[3] = pack2bf(b[2], b[3]);
    *(u32x4*)(d + off) = r;
}

// ---------------------------------------------------------------------------
// GEMM: C[M,N] = A[M,K]*B[N,K]^T, bf16 in, fp32 accum. 128x128 tile, BK=64,
// global_load_lds dwordx4. LDS [128][64] elems, XOR swizzle: logical 16B
// chunk q of row r at physical chunk q ^ (r&7) -> 2-way on banks (free).
// EPI=0: cols<2048 -> Cq bf16 (stride 2048); cols>=2048 (V) packed-scatter
//        to Cv = Vt[(b*16+h)*64+d][l] bf16.   EPI=1: Cf fp32 + bias.
// grid.x = n-tiles (24 or 8, both ≡ 0 mod 8): same-B-tile blocks share XCD.
// ---------------------------------------------------------------------------
template<int EPI>
__global__ __launch_bounds__(256) void gemm16(
    const unsigned short* __restrict__ A, const unsigned short* __restrict__ Bm,
    unsigned short* __restrict__ Cq, unsigned short* __restrict__ Cv,
    float* __restrict__ Cf, const float* __restrict__ bias,
    int N, int K)
{
    __shared__ unsigned short As[128 * 64];
    __shared__ unsigned short Bs[128 * 64];
    const int tid = threadIdx.x, lane = tid & 63, wave = tid >> 6;
    const int quad = lane >> 4, l16 = lane & 15;
    const int wm = (wave >> 1) * 64, wn = (wave & 1) * 64;
    const int m0 = blockIdx.y * 128, n0 = blockIdx.x * 128;

    const int prow = tid >> 3;
    const int qch  = (tid & 7) ^ (prow & 7);
    const unsigned short* gA[4];
    const unsigned short* gB[4];
    #pragma unroll
    for (int c = 0; c < 4; ++c) {
        gA[c] = A + (size_t)(m0 + c * 32 + prow) * K + qch * 8;
        gB[c] = Bm + (size_t)(n0 + c * 32 + prow) * K + qch * 8;
    }
    const int sw = l16 & 7;   // frag-read swizzle

    f32x4 acc[4][4] = {};
    for (int k0 = 0; k0 < K; k0 += 64) {
        __syncthreads();
        #pragma unroll
        for (int c = 0; c < 4; ++c) {
            GLOAD_LDS(gA[c], As + (c * 256 + tid) * 8);
            GLOAD_LDS(gB[c], Bs + (c * 256 + tid) * 8);
            gA[c] += 64; gB[c] += 64;
        }
        __syncthreads();
        #pragma unroll
        for (int s = 0; s < 2; ++s) {
            s16x8 af[4], bf[4];
            const int pc = ((s * 4 + quad) ^ sw) * 8;
            #pragma unroll
            for (int i = 0; i < 4; ++i)
                af[i] = *(const s16x8*)(As + (wm + i * 16 + l16) * 64 + pc);
            #pragma unroll
            for (int j = 0; j < 4; ++j)
                bf[j] = *(const s16x8*)(Bs + (wn + j * 16 + l16) * 64 + pc);
            #pragma unroll
            for (int i = 0; i < 4; ++i)
                #pragma unroll
                for (int j = 0; j < 4; ++j)
                    acc[i][j] = __builtin_amdgcn_mfma_f32_16x16x32_bf16(af[i], bf[j], acc[i][j], 0, 0, 0);
        }
    }

    // epilogue: C/D layout col=lane&15, row=quad*4+reg
    if (EPI == 1) {
        #pragma unroll
        for (int j = 0; j < 4; ++j) {
            int col = n0 + wn + j * 16 + l16;
            float bv = bias[col];
            #pragma unroll
            for (int i = 0; i < 4; ++i)
                #pragma unroll
                for (int r = 0; r < 4; ++r)
                    Cf[(size_t)(m0 + wm + i * 16 + quad * 4 + r) * N + col] = acc[i][j][r] + bv;
        }
    } else if (n0 < 2048) {
        #pragma unroll
        for (int j = 0; j < 4; ++j) {
            int col = n0 + wn + j * 16 + l16;
            #pragma unroll
            for (int i = 0; i < 4; ++i)
                #pragma unroll
                for (int r = 0; r < 4; ++r)
                    Cq[(size_t)(m0 + wm + i * 16 + quad * 4 + r) * 2048 + col] = f2bf(acc[i][j][r]);
        }
    } else {
        // V region: lane's r=0..3 are 4 consecutive l -> one 8B packed store
        #pragma unroll
        for (int j = 0; j < 4; ++j) {
            int dcol = n0 + wn + j * 16 + l16 - 2048;
            int hh = dcol >> 6, dd = dcol & 63;
            #pragma unroll
            for (int i = 0; i < 4; ++i) {
                int row = m0 + wm + i * 16 + quad * 4;
                int bb = row >> 10, l = row & 1023;
                u32x2 pw;
                pw[0] = pack2bf(acc[i][j][0], acc[i][j][1]);
                pw[1] = pack2bf(acc[i][j][2], acc[i][j][3]);
                *(u32x2*)(Cv + (size_t)((bb * 16 + hh) * 64 + dd) * 1024 + l) = pw;
            }
        }
    }
}

// ---------------------------------------------------------------------------
// Flash attention, no-max softmax, S^T trick, async-staged K/V, 128 q-rows
// per block (two 16-row halves per wave share each staged K/V tile).
// Grid (128 bh, 8 qtile): linear id = bh + qtile*128, id%8 = bh%8 -> same
// head's blocks co-locate on one XCD (K/V L2-resident after first touch).
// LDS 25.2 KB -> 6 blocks/CU.
// ---------------------------------------------------------------------------
__global__ __launch_bounds__(256) void attn(
    const unsigned short* __restrict__ qk, const unsigned short* __restrict__ Vt,
    unsigned short* __restrict__ O)
{
    __shared__ unsigned short Ks[64 * 64];     // [kv_local][d]  (swizzled)
    __shared__ unsigned short Vs[64 * 64];     // [d][kv_local]  (swizzled)
    __shared__ unsigned short Ps[4][16 * 72];  // per wave (in-order DS: 1 buf)

    const int bh = blockIdx.x, b = bh >> 4, hh = bh & 15;
    const int q0 = blockIdx.y * 128;
    const int tid = threadIdx.x, lane = tid & 63, wave = tid >> 6;
    const int quad = lane >> 4, l16 = lane & 15;

    // Q frags direct from global: B-operand, n=q, k=s*32+quad*8
    s16x8 qf[2][2];
    #pragma unroll
    for (int h = 0; h < 2; ++h) {
        const unsigned short* qrow =
            qk + (size_t)(b * 1024 + q0 + h * 64 + wave * 16 + l16) * 2048 + hh * 64;
        qf[h][0] = *(const s16x8*)(qrow + quad * 8);
        qf[h][1] = *(const s16x8*)(qrow + 32 + quad * 8);
    }

    // K/V staging: wave covers row-groups g0,g1 (8 rows x 8 chunks = 1KB);
    // physical (row = g*8 + (lane>>3), pc = lane&7); logical chunk = pc ^ row&7.
    const int rl = lane >> 3;
    const int qc = (lane & 7) ^ rl;
    const int g0 = wave * 2, g1 = g0 + 1;
    const unsigned short* srcK0 = qk + (size_t)(b * 1024 + g0 * 8 + rl) * 2048 + 1024 + hh * 64 + qc * 8;
    const unsigned short* srcK1 = qk + (size_t)(b * 1024 + g1 * 8 + rl) * 2048 + 1024 + hh * 64 + qc * 8;
    const unsigned short* srcV0 = Vt + (size_t)(bh * 64 + g0 * 8 + rl) * 1024 + qc * 8;
    const unsigned short* srcV1 = Vt + (size_t)(bh * 64 + g1 * 8 + rl) * 1024 + qc * 8;
    unsigned short* dK0 = Ks + g0 * 512 + lane * 8;
    unsigned short* dK1 = Ks + g1 * 512 + lane * 8;
    unsigned short* dV0 = Vs + g0 * 512 + lane * 8;
    unsigned short* dV1 = Vs + g1 * 512 + lane * 8;

    const int sw = l16 & 7;   // frag-read swizzle

    f32x4 Oacc[2][4] = {};
    float lsum[2] = {0.0f, 0.0f};

    for (int kv = 0; kv < 1024; kv += 64) {
        __syncthreads();
        GLOAD_LDS(srcK0, dK0);
        GLOAD_LDS(srcK1, dK1);
        GLOAD_LDS(srcV0, dV0);
        GLOAD_LDS(srcV1, dV1);
        srcK0 += (size_t)64 * 2048; srcK1 += (size_t)64 * 2048;
        srcV0 += 64; srcV1 += 64;
        __syncthreads();   // vmcnt(0) drain -> K,V in LDS

        #pragma unroll
        for (int h = 0; h < 2; ++h) {
            unsigned short* Pw = &Ps[wave][0];
            // S^T = K Q^T : rows kv = j*16+quad*4+r, col q = l16
            f32x4 Sacc[4] = {};
            #pragma unroll
            for (int j = 0; j < 4; ++j) {
                #pragma unroll
                for (int s = 0; s < 2; ++s) {
                    s16x8 kf = *(const s16x8*)(Ks + (j * 16 + l16) * 64 + ((s * 4 + quad) ^ sw) * 8);
                    Sacc[j] = __builtin_amdgcn_mfma_f32_16x16x32_bf16(kf, qf[h][s], Sacc[j], 0, 0, 0);
                }
            }
            // p = exp(s/8); per-lane row-sum; pack + ds_write_b64 P[q=l16][kv]
            #pragma unroll
            for (int j = 0; j < 4; ++j) {
                float p0 = __expf(Sacc[j][0] * 0.125f);
                float p1 = __expf(Sacc[j][1] * 0.125f);
                float p2 = __expf(Sacc[j][2] * 0.125f);
                float p3 = __expf(Sacc[j][3] * 0.125f);
                lsum[h] += (p0 + p1) + (p2 + p3);
                u32x2 pw;
                pw[0] = pack2bf(p0, p1);
                pw[1] = pack2bf(p2, p3);
                *(u32x2*)(Pw + l16 * 72 + j * 16 + quad * 4) = pw;
            }
            asm volatile("s_waitcnt lgkmcnt(0)" ::: "memory");  // wave-local P ready
            // O += P V^T : A=P[m=q], B=Vs[n=d]
            #pragma unroll
            for (int s = 0; s < 2; ++s) {
                s16x8 pf = *(const s16x8*)(Pw + l16 * 72 + s * 32 + quad * 8);
                #pragma unroll
                for (int j = 0; j < 4; ++j) {
                    s16x8 vf = *(const s16x8*)(Vs + (j * 16 + l16) * 64 + ((s * 4 + quad) ^ sw) * 8);
                    Oacc[h][j] = __builtin_amdgcn_mfma_f32_16x16x32_bf16(pf, vf, Oacc[h][j], 0, 0, 0);
                }
            }
        }
    }

    // row-sum reduce + write
    #pragma unroll
    for (int h = 0; h < 2; ++h) {
        float ls = lsum[h];
        ls += __shfl_xor(ls, 16, 64);
        ls += __shfl_xor(ls, 32, 64);
        float rinv[4];
        #pragma unroll
        for (int r = 0; r < 4; ++r)
            rinv[r] = 1.0f / __shfl(ls, quad * 4 + r, 64);
        #pragma unroll
        for (int j = 0; j < 4; ++j)
            #pragma unroll
            for (int r = 0; r < 4; ++r) {
                int row = q0 + h * 64 + wave * 16 + quad * 4 + r;
                int col = hh * 64 + j * 16 + l16;
                O[(size_t)(b * 1024 + row) * 1024 + col] = f2bf(Oacc[h][j][r] * rinv[r]);
            }
    }
}

extern "C" void kernel_launch(void* const* d_in, const int* in_sizes, int n_in,
                              void* d_out, int out_size, void* d_ws, size_t ws_size,
                              hipStream_t stream) {
    const float* x     = (const float*)d_in[0];   // [8192,1024]
    const float* w_qkv = (const float*)d_in[1];   // [3072,1024]
    const float* w_out = (const float*)d_in[2];   // [1024,1024]
    const float* b_out = (const float*)d_in[3];   // [1024]
    float* out = (float*)d_out;                   // [8192,1024] fp32

    const int nx = 8192 * 1024, nwq = 3072 * 1024, nwo = 1024 * 1024;
    unsigned short* xb  = (unsigned short*)d_ws;          // 16.8 MB (dead after gemm1)
    unsigned short* wqb = xb + nx;                        //  6.3 MB
    unsigned short* wob = wqb + nwq;                      //  2.1 MB
    unsigned short* qkb = wob + nwo;                      // [8192,2048] Q|K, 33.6 MB
    unsigned short* Vt  = qkb + (size_t)8192 * 2048;      // [128*64,1024], 16.8 MB
    unsigned short* Ob  = xb;                             // alias: xb dead after gemm1

    dim3 blk(256);
    cvt3<<<6144, blk, 0, stream>>>(x, xb, nx, w_qkv, wqb, nwq, w_out, wob, nwo);
    gemm16<0><<<dim3(24, 64), blk, 0, stream>>>(xb, wqb, qkb, Vt, nullptr, nullptr, 3072, 1024);
    attn<<<dim3(128, 8), blk, 0, stream>>>(qkb, Vt, Ob);
    gemm16<1><<<dim3(8, 64), blk, 0, stream>>>(Ob, wob, nullptr, nullptr, out, b_out, 1024, 1024);
}